// Round 10
// baseline (4990.820 us; speedup 1.0000x reference)
//
#include <hip/hip_runtime.h>
#include <hip/hip_fp16.h>
#include <cstddef>

#define TT 2048   // time steps
#define BB 256    // batch
#define DD 32     // input dim
#define HH 64     // hidden
#define GG 256    // 4*H

__device__ __forceinline__ float sigmf(float v)  { return 1.0f / (1.0f + __expf(-v)); }
__device__ __forceinline__ float tanhf_(float v) { return 2.0f / (1.0f + __expf(-2.0f * v)) - 1.0f; }
__device__ __forceinline__ __half2 f_as_h2(float f) { union { float f; __half2 h; } c; c.f = f; return c.h; }
__device__ __forceinline__ __half2 u_as_h2(unsigned v) { union { unsigned u; __half2 h; } c; c.u = v; return c.h; }

// ---------------- pre-kernel: zx[(b*TT+t)*256 + u*4+g] = x[b,t,:]·W1[:,g*64+u] + b1, f16 ----------------
__global__ __launch_bounds__(256)
void zx_pre(const float* __restrict__ x, const float* __restrict__ W1,
            const float* __restrict__ b1, __half* __restrict__ zx)
{
    const int bb = blockIdx.x, tb = blockIdx.y, zr = threadIdx.x;  // zr = u*4+g
    __shared__ float xs[8][DD];
    const float* xb = x + ((size_t)bb * TT + (size_t)tb * 8) * DD;
    xs[zr >> 5][zr & 31] = xb[zr];
    __syncthreads();

    const int u = zr >> 2, g = zr & 3;
    const int colW = g * HH + u;
    float wcol[DD];
    #pragma unroll
    for (int d = 0; d < DD; ++d) wcol[d] = W1[d * GG + colW];
    const float bias = b1[colW];

    __half* zb = zx + ((size_t)bb * TT + (size_t)tb * 8) * 256 + zr;
    #pragma unroll
    for (int r8 = 0; r8 < 8; ++r8) {
        float z0 = bias, z1 = 0.f, z2 = 0.f, z3 = 0.f;
        #pragma unroll
        for (int d = 0; d < DD; d += 4) {
            z0 += xs[r8][d+0] * wcol[d+0];
            z1 += xs[r8][d+1] * wcol[d+1];
            z2 += xs[r8][d+2] * wcol[d+2];
            z3 += xs[r8][d+3] * wcol[d+3];
        }
        zb[(size_t)r8 * 256] = __float2half((z0 + z1) + (z2 + z3));
    }
}

// ---------------- recurrence: ONE WAVE per batch row, ZERO barriers ----------------
// Lane = unit u. Per step (pure program-order dataflow within the wave):
//   read h1(n-1) [LDS bcast] -> L1 dots (zx + U1·h1, 128 hfma2) -> c1/h1 update
//   -> ds_write h1(n) -> read back -> L2 dots (W2·h1(n) + U2·h2(n-1), 256 hfma2)
//   -> c2/h2 update -> ds_write h2(n) -> butterfly-reduce projection -> out[n].
// No s_barrier anywhere: wave-synchronous LDS (lgkmcnt only). Weights (384
// half2) live in the unified VGPR/AGPR file at 1 wave/SIMD (512-reg budget).
__global__ __launch_bounds__(64, 1)
void dlstm_rec(const __half* __restrict__ zx,
               const float* __restrict__ U1, const float* __restrict__ W2,
               const float* __restrict__ U2, const float* __restrict__ b2,
               const float* __restrict__ Wd, const float* __restrict__ bd,
               float* __restrict__ out)
{
    const int u = threadIdx.x & 63;
    const int b = blockIdx.x;

    __shared__ __align__(16) __half h1b[HH];
    __shared__ __align__(16) __half h2b[HH];
    h1b[u] = __float2half(0.f);
    h2b[u] = __float2half(0.f);

    // loop-invariant weight columns, fp16-packed
    __half2 u1w[4][32], w2w[4][32], u2w[4][32];
    float bz2[4];
    #pragma unroll
    for (int g = 0; g < 4; ++g) {
        const int col = g * HH + u;
        #pragma unroll
        for (int j = 0; j < 32; ++j) {
            u1w[g][j] = __floats2half2_rn(U1[(2*j) * GG + col], U1[(2*j+1) * GG + col]);
            w2w[g][j] = __floats2half2_rn(W2[(2*j) * GG + col], W2[(2*j+1) * GG + col]);
            u2w[g][j] = __floats2half2_rn(U2[(2*j) * GG + col], U2[(2*j+1) * GG + col]);
        }
        bz2[g] = b2[col];
    }
    const float wdu = Wd[u], bd0 = bd[0];
    float c1 = 0.f, c2 = 0.f;

    const __half* zr_ = zx + (size_t)b * TT * 256 + u * 4;   // 4 gates of my unit
    uint2 zc = *(const uint2*)zr_;
    float* outb = out + (size_t)b * TT;

    for (int n = 0; n < TT; ++n) {
        // prefetch zx(n+1): in flight under the whole step
        const int tn = (n + 1 < TT) ? n + 1 : n;
        const uint2 zn = *(const uint2*)(zr_ + (size_t)tn * 256);

        __half2 hh[32];
        // ---- L1: h1(n-1) broadcast read + dots ----
        #pragma unroll
        for (int j = 0; j < 8; ++j) {
            float4 r = ((const float4*)h1b)[j];
            hh[4*j+0] = f_as_h2(r.x); hh[4*j+1] = f_as_h2(r.y);
            hh[4*j+2] = f_as_h2(r.z); hh[4*j+3] = f_as_h2(r.w);
        }
        float zg[4];
        #pragma unroll
        for (int g = 0; g < 4; ++g) {
            __half2 s0 = __float2half2_rn(0.f), s1 = s0;
            #pragma unroll
            for (int j = 0; j < 16; ++j) s0 = __hfma2(u1w[g][j], hh[j], s0);
            #pragma unroll
            for (int j = 16; j < 32; ++j) s1 = __hfma2(u1w[g][j], hh[j], s1);
            __half2 s = __hadd2(s0, s1);
            zg[g] = __low2float(s) + __high2float(s);
        }
        {
            const __half2 zl = u_as_h2(zc.x), zh = u_as_h2(zc.y);
            zg[0] += __low2float(zl); zg[1] += __high2float(zl);
            zg[2] += __low2float(zh); zg[3] += __high2float(zh);
        }
        float gi = sigmf(zg[0]), gf = sigmf(zg[1]);
        float gc = tanhf_(zg[2]), go = sigmf(zg[3]);
        c1 = gf * c1 + gi * gc;
        const float h1n = go * tanhf_(c1);
        h1b[u] = __float2half(h1n);          // wave-synchronous exchange (no barrier)

        // ---- L2: W2·h1(n) ----
        #pragma unroll
        for (int j = 0; j < 8; ++j) {
            float4 r = ((const float4*)h1b)[j];
            hh[4*j+0] = f_as_h2(r.x); hh[4*j+1] = f_as_h2(r.y);
            hh[4*j+2] = f_as_h2(r.z); hh[4*j+3] = f_as_h2(r.w);
        }
        __half2 acc0[4], acc1[4];
        #pragma unroll
        for (int g = 0; g < 4; ++g) {
            __half2 s0 = __float2half2_rn(0.f), s1 = s0;
            #pragma unroll
            for (int j = 0; j < 16; ++j) s0 = __hfma2(w2w[g][j], hh[j], s0);
            #pragma unroll
            for (int j = 16; j < 32; ++j) s1 = __hfma2(w2w[g][j], hh[j], s1);
            acc0[g] = s0; acc1[g] = s1;
        }
        // ---- L2: + U2·h2(n-1) ----
        #pragma unroll
        for (int j = 0; j < 8; ++j) {
            float4 r = ((const float4*)h2b)[j];
            hh[4*j+0] = f_as_h2(r.x); hh[4*j+1] = f_as_h2(r.y);
            hh[4*j+2] = f_as_h2(r.z); hh[4*j+3] = f_as_h2(r.w);
        }
        #pragma unroll
        for (int g = 0; g < 4; ++g) {
            #pragma unroll
            for (int j = 0; j < 16; ++j) acc0[g] = __hfma2(u2w[g][j], hh[j], acc0[g]);
            #pragma unroll
            for (int j = 16; j < 32; ++j) acc1[g] = __hfma2(u2w[g][j], hh[j], acc1[g]);
            __half2 s = __hadd2(acc0[g], acc1[g]);
            zg[g] = __low2float(s) + __high2float(s) + bz2[g];
        }
        gi = sigmf(zg[0]); gf = sigmf(zg[1]);
        gc = tanhf_(zg[2]); go = sigmf(zg[3]);
        c2 = gf * c2 + gi * gc;
        const float h2n = go * tanhf_(c2);
        h2b[u] = __float2half(h2n);

        // projection: off the recurrence-critical path (feeds only the store)
        float v = h2n * wdu;
        v += __shfl_xor(v, 1, 64);
        v += __shfl_xor(v, 2, 64);
        v += __shfl_xor(v, 4, 64);
        v += __shfl_xor(v, 8, 64);
        v += __shfl_xor(v, 16, 64);
        v += __shfl_xor(v, 32, 64);
        if (u == 0) outb[n] = sigmf(v + bd0);

        zc = zn;
    }
}

// ---------------- fallback: R8 kernel (1921us proven) if ws too small ----------------
__global__ __launch_bounds__(512, 2)
void dlstm_fb(const float* __restrict__ x,
              const float* __restrict__ W1, const float* __restrict__ U1,
              const float* __restrict__ b1,
              const float* __restrict__ W2, const float* __restrict__ U2,
              const float* __restrict__ b2,
              const float* __restrict__ Wd, const float* __restrict__ bd,
              float* __restrict__ out)
{
    const int tid = threadIdx.x, b = blockIdx.x;
    const int wid = tid >> 6, l = tid & 63;
    const int kq = l >> 4, ul = l & 15;

    __shared__ __align__(16) __half h1b[2][HH];
    __shared__ __align__(16) __half h2b[2][HH];
    __shared__ float pbuf[2][4];

    if (tid < HH) {
        h1b[0][tid] = __float2half(0.f); h1b[1][tid] = __float2half(0.f);
        h2b[0][tid] = __float2half(0.f); h2b[1][tid] = __float2half(0.f);
    }
    if (tid < 8) pbuf[tid >> 2][tid & 3] = 0.f;
    __syncthreads();

    if (wid < 4) {
        const int u = (wid << 4) + ul;
        __half2 u1p[4][8];
        #pragma unroll
        for (int gp = 0; gp < 4; ++gp)
            #pragma unroll
            for (int j = 0; j < 8; ++j)
                u1p[gp][j] = __floats2half2_rn(U1[(kq*16 + 2*j) * GG + gp*HH + u],
                                               U1[(kq*16 + 2*j + 1) * GG + gp*HH + u]);
        __half2 w1p[4][4];
        #pragma unroll
        for (int gp = 0; gp < 4; ++gp)
            #pragma unroll
            for (int j = 0; j < 4; ++j)
                w1p[gp][j] = __floats2half2_rn(W1[(kq*8 + 2*j) * GG + gp*HH + u],
                                               W1[(kq*8 + 2*j + 1) * GG + gp*HH + u]);
        const float b1k = b1[kq * HH + u];
        const float bd0 = bd[0];
        float c1 = 0.f;
        const float* xr = x + (size_t)b * TT * DD + kq * 8;
        float4 xa = *(const float4*)(xr);
        float4 xb = *(const float4*)(xr + 4);

        for (int n = 0; n < TT + 2; ++n) {
            const int p = n & 1;
            if (n < TT) {
                const size_t tn = (n + 1 < TT) ? (size_t)(n + 1) : (size_t)n;
                float4 na = *(const float4*)(xr + tn * DD);
                float4 nb = *(const float4*)(xr + tn * DD + 4);
                __half2 xx[4];
                xx[0] = __floats2half2_rn(xa.x, xa.y);
                xx[1] = __floats2half2_rn(xa.z, xa.w);
                xx[2] = __floats2half2_rn(xb.x, xb.y);
                xx[3] = __floats2half2_rn(xb.z, xb.w);
                const __half2* hp = (const __half2*)&h1b[p][kq * 16];
                __half2 hh[8];
                #pragma unroll
                for (int j = 0; j < 8; ++j) hh[j] = hp[j];
                float ag[4];
                #pragma unroll
                for (int gp = 0; gp < 4; ++gp) {
                    __half2 s = __float2half2_rn(0.f);
                    #pragma unroll
                    for (int j = 0; j < 8; ++j) s = __hfma2(u1p[gp][j], hh[j], s);
                    #pragma unroll
                    for (int j = 0; j < 4; ++j) s = __hfma2(w1p[gp][j], xx[j], s);
                    ag[gp] = __low2float(s) + __high2float(s);
                }
                float t1 = (kq & 1) ? ag[0] : ag[1];
                float t2 = (kq & 1) ? ag[2] : ag[3];
                float r1 = __shfl_xor(t1, 16, 64);
                float r2 = __shfl_xor(t2, 16, 64);
                float m1 = (kq & 1) ? ag[1] : ag[0];
                float m2 = (kq & 1) ? ag[3] : ag[2];
                float s1 = m1 + r1, s2 = m2 + r2;
                float t3 = (kq < 2) ? s2 : s1;
                float r3 = __shfl_xor(t3, 32, 64);
                float mine = (kq < 2) ? s1 : s2;
                float z = mine + r3 + b1k;
                float a = (kq == 2) ? tanhf_(z) : sigmf(z);
                float g16 = __shfl_xor(a, 16, 64);
                float g32 = __shfl_xor(a, 32, 64);
                float g48 = __shfl_xor(g16, 32, 64);
                c1 = g16 * c1 + a * g32;
                float h = g48 * tanhf_(c1);
                if (kq == 0) h1b[p ^ 1][u] = __float2half(h);
                xa = na; xb = nb;
            }
            if (tid == 0 && n >= 2) {
                float s = pbuf[p][0] + pbuf[p][1] + pbuf[p][2] + pbuf[p][3];
                out[(size_t)b * TT + (n - 2)] = sigmf(s + bd0);
            }
            __syncthreads();
        }
    } else {
        const int w2i = wid - 4;
        const int u = (w2i << 4) + ul;
        __half2 w2p[4][8], u2p[4][8];
        #pragma unroll
        for (int gp = 0; gp < 4; ++gp)
            #pragma unroll
            for (int j = 0; j < 8; ++j) {
                w2p[gp][j] = __floats2half2_rn(W2[(kq*16 + 2*j) * GG + gp*HH + u],
                                               W2[(kq*16 + 2*j + 1) * GG + gp*HH + u]);
                u2p[gp][j] = __floats2half2_rn(U2[(kq*16 + 2*j) * GG + gp*HH + u],
                                               U2[(kq*16 + 2*j + 1) * GG + gp*HH + u]);
            }
        const float b2k = b2[kq * HH + u];
        const float wdu = Wd[u];
        float c2 = 0.f;

        for (int n = 0; n < TT + 2; ++n) {
            const int p = n & 1;
            if (n >= 1 && n <= TT) {
                const __half2* h1p = (const __half2*)&h1b[p][kq * 16];
                const __half2* h2p = (const __half2*)&h2b[p][kq * 16];
                __half2 hh1[8], hh2[8];
                #pragma unroll
                for (int j = 0; j < 8; ++j) { hh1[j] = h1p[j]; hh2[j] = h2p[j]; }
                float ag[4];
                #pragma unroll
                for (int gp = 0; gp < 4; ++gp) {
                    __half2 s = __float2half2_rn(0.f);
                    #pragma unroll
                    for (int j = 0; j < 8; ++j) s = __hfma2(w2p[gp][j], hh1[j], s);
                    #pragma unroll
                    for (int j = 0; j < 8; ++j) s = __hfma2(u2p[gp][j], hh2[j], s);
                    ag[gp] = __low2float(s) + __high2float(s);
                }
                float t1 = (kq & 1) ? ag[0] : ag[1];
                float t2 = (kq & 1) ? ag[2] : ag[3];
                float r1 = __shfl_xor(t1, 16, 64);
                float r2 = __shfl_xor(t2, 16, 64);
                float m1 = (kq & 1) ? ag[1] : ag[0];
                float m2 = (kq & 1) ? ag[3] : ag[2];
                float s1 = m1 + r1, s2 = m2 + r2;
                float t3 = (kq < 2) ? s2 : s1;
                float r3 = __shfl_xor(t3, 32, 64);
                float mine = (kq < 2) ? s1 : s2;
                float z = mine + r3 + b2k;
                float a = (kq == 2) ? tanhf_(z) : sigmf(z);
                float g16 = __shfl_xor(a, 16, 64);
                float g32 = __shfl_xor(a, 32, 64);
                float g48 = __shfl_xor(g16, 32, 64);
                c2 = g16 * c2 + a * g32;
                float h = g48 * tanhf_(c2);
                if (kq == 0) h2b[p ^ 1][u] = __float2half(h);
                float v = (kq == 0) ? h * wdu : 0.f;
                v += __shfl_xor(v, 1, 64);
                v += __shfl_xor(v, 2, 64);
                v += __shfl_xor(v, 4, 64);
                v += __shfl_xor(v, 8, 64);
                if (l == 0) pbuf[p ^ 1][w2i] = v;
            }
            __syncthreads();
        }
    }
}

extern "C" void kernel_launch(void* const* d_in, const int* in_sizes, int n_in,
                              void* d_out, int out_size, void* d_ws, size_t ws_size,
                              hipStream_t stream) {
    const float* x  = (const float*)d_in[0];
    const float* W1 = (const float*)d_in[1];
    const float* U1 = (const float*)d_in[2];
    const float* b1 = (const float*)d_in[3];
    const float* W2 = (const float*)d_in[4];
    const float* U2 = (const float*)d_in[5];
    const float* b2 = (const float*)d_in[6];
    const float* Wd = (const float*)d_in[7];
    const float* bd = (const float*)d_in[8];
    float* out = (float*)d_out;

    const size_t need_f16 = (size_t)BB * TT * GG * sizeof(__half);  // 268 MB (proven fits, R7)

    if (ws_size >= need_f16) {
        __half* zxw = (__half*)d_ws;
        zx_pre<<<dim3(BB, TT / 8), dim3(256), 0, stream>>>(x, W1, b1, zxw);
        dlstm_rec<<<dim3(BB), dim3(64), 0, stream>>>(zxw, U1, W2, U2, b2, Wd, bd, out);
    } else {
        dlstm_fb<<<dim3(BB), dim3(512), 0, stream>>>(x, W1, U1, b1, W2, U2, b2, Wd, bd, out);
    }
}

// Round 11
// 2367.043 us; speedup vs baseline: 2.1085x; 2.1085x over previous
//
#include <hip/hip_runtime.h>
#include <hip/hip_fp16.h>
#include <cstddef>

#define TT 2048   // time steps
#define BB 256    // batch
#define DD 32     // input dim
#define HH 64     // hidden
#define GG 256    // 4*H

__device__ __forceinline__ float sigmf(float v)  { return 1.0f / (1.0f + __expf(-v)); }
__device__ __forceinline__ float tanhf_(float v) { return 2.0f / (1.0f + __expf(-2.0f * v)) - 1.0f; }
// single-sigmoid branchless activation: tanh(z) = 2*sigm(2z)-1
__device__ __forceinline__ float act(float z, bool istanh) {
    float zin = istanh ? z + z : z;
    float s = 1.0f / (1.0f + __expf(-zin));
    return istanh ? 2.0f * s - 1.0f : s;
}
__device__ __forceinline__ __half2 f_as_h2(float f) { union { float f; __half2 h; } c; c.f = f; return c.h; }

// One block per batch row; 1024 threads = 16 waves (4/SIMD -- double R8's
// occupancy; R9/R10 proved fewer waves regress). Waves 0-7: layer-1 engine
// (one step ahead); waves 8-15: layer-2 engine + projection partials.
// Thread map: unit u = (wid&7)*8 + (l&7); K-chunk kc = l>>3 (8 chunks).
// Per step: 1-2 ds_read_b128, 24-32 v_pk_fma_f16, 4-shuffle reduce-scatter
// (lane kc finalizes gate sg = 2*(kc&1)+((kc>>1)&1)), 3-shuffle gather,
// redundant in-lane cell update; kc==0 lanes commit h. One barrier per step.
__global__ __launch_bounds__(1024)
void dlstm_kernel(const float* __restrict__ x,
                  const float* __restrict__ W1, const float* __restrict__ U1,
                  const float* __restrict__ b1,
                  const float* __restrict__ W2, const float* __restrict__ U2,
                  const float* __restrict__ b2,
                  const float* __restrict__ Wd, const float* __restrict__ bd,
                  float* __restrict__ out)
{
    const int tid = threadIdx.x, b = blockIdx.x;
    const int wid = tid >> 6;          // 0..15
    const int l   = tid & 63;
    const int kc  = l >> 3;            // K-chunk 0..7
    const int ul  = l & 7;
    const int u   = (wid & 7) * 8 + ul;            // unit 0..63
    const int sg  = 2 * (kc & 1) + ((kc >> 1) & 1); // gate this lane finalizes
    const bool istanh = (sg == 2);

    __shared__ __align__(16) __half h1b[2][HH];
    __shared__ __align__(16) __half h2b[2][HH];
    __shared__ float pbuf[2][8];

    if (tid < HH) {
        h1b[0][tid] = __float2half(0.f); h1b[1][tid] = __float2half(0.f);
        h2b[0][tid] = __float2half(0.f); h2b[1][tid] = __float2half(0.f);
    }
    if (tid < 16) pbuf[tid >> 3][tid & 7] = 0.f;
    __syncthreads();

    if (wid < 8) {
        // ================= layer-1 engine: computes h1(n) at iter n =================
        // U1 chunk: rows [kc*8, kc*8+8) x 4 gate-cols of u; W1 chunk: rows [kc*4,+4)
        __half2 u1w[4][4], w1w[4][2];
        #pragma unroll
        for (int g = 0; g < 4; ++g) {
            const int col = g * HH + u;
            #pragma unroll
            for (int j = 0; j < 4; ++j)
                u1w[g][j] = __floats2half2_rn(U1[(kc*8 + 2*j) * GG + col],
                                              U1[(kc*8 + 2*j + 1) * GG + col]);
            #pragma unroll
            for (int j = 0; j < 2; ++j)
                w1w[g][j] = __floats2half2_rn(W1[(kc*4 + 2*j) * GG + col],
                                              W1[(kc*4 + 2*j + 1) * GG + col]);
        }
        const float bz  = b1[sg * HH + u];
        const float bd0 = bd[0];
        float c1 = 0.f;

        const float* xr = x + (size_t)b * TT * DD + kc * 4;   // my 4 x-elems
        float4 xc = *(const float4*)xr;

        for (int n = 0; n < TT + 2; ++n) {
            const int p = n & 1;
            if (n < TT) {
                const size_t tn = (n + 1 < TT) ? (size_t)(n + 1) : (size_t)n;
                float4 xn = *(const float4*)(xr + tn * DD);   // prefetch x(n+1)

                float4 hv = ((const float4*)h1b[p])[kc];      // my 8 h-elems: 1 b128
                __half2 hh0 = f_as_h2(hv.x), hh1 = f_as_h2(hv.y);
                __half2 hh2 = f_as_h2(hv.z), hh3 = f_as_h2(hv.w);
                __half2 xh0 = __floats2half2_rn(xc.x, xc.y);
                __half2 xh1 = __floats2half2_rn(xc.z, xc.w);

                float ag[4];
                #pragma unroll
                for (int g = 0; g < 4; ++g) {
                    __half2 s = __float2half2_rn(0.f);
                    s = __hfma2(u1w[g][0], hh0, s);
                    s = __hfma2(u1w[g][1], hh1, s);
                    s = __hfma2(u1w[g][2], hh2, s);
                    s = __hfma2(u1w[g][3], hh3, s);
                    s = __hfma2(w1w[g][0], xh0, s);
                    s = __hfma2(w1w[g][1], xh1, s);
                    ag[g] = __low2float(s) + __high2float(s);
                }
                // reduce-scatter over kc (lane bits 3,4,5); lane ends with gate sg
                float s0 = (kc & 1) ? ag[0] : ag[2];
                float s1 = (kc & 1) ? ag[1] : ag[3];
                float t0 = __shfl_xor(s0, 8, 64);
                float t1 = __shfl_xor(s1, 8, 64);
                float ga = ((kc & 1) ? ag[2] : ag[0]) + t0;   // gate 2*(kc&1)
                float gb = ((kc & 1) ? ag[3] : ag[1]) + t1;   // gate 2*(kc&1)+1
                const bool hi2 = ((kc >> 1) & 1);
                float ms = hi2 ? ga : gb;
                float mk = hi2 ? gb : ga;
                float zp = mk + __shfl_xor(ms, 16, 64);        // gate sg over 32 rows
                float z  = zp + __shfl_xor(zp, 32, 64) + bz;   // full sum

                float a = act(z, istanh);
                // gather: a=sg, x8=sg^2, x16=sg^1, x24=sg^3
                float x8  = __shfl_xor(a, 8, 64);
                float x16 = __shfl_xor(a, 16, 64);
                float x24 = __shfl_xor(x8, 16, 64);
                float gi = (sg==0) ? a   : (sg==1) ? x16 : (sg==2) ? x8  : x24;
                float gf = (sg==0) ? x16 : (sg==1) ? a   : (sg==2) ? x24 : x8;
                float gc = (sg==0) ? x8  : (sg==1) ? x24 : (sg==2) ? a   : x16;
                float go = (sg==0) ? x24 : (sg==1) ? x8  : (sg==2) ? x16 : a;
                c1 = gf * c1 + gi * gc;                       // identical in all kc lanes
                float h = go * tanhf_(c1);
                if (kc == 0) h1b[p ^ 1][u] = __float2half(h);
                xc = xn;
            }
            // out(n-2): sum the 8 L2-wave partials of h2(n-2)
            if (wid == 0 && l == 0 && n >= 2) {
                float s = ((pbuf[p][0] + pbuf[p][1]) + (pbuf[p][2] + pbuf[p][3]))
                        + ((pbuf[p][4] + pbuf[p][5]) + (pbuf[p][6] + pbuf[p][7]));
                out[(size_t)b * TT + (n - 2)] = sigmf(s + bd0);
            }
            __syncthreads();
        }
    } else {
        // ================= layer-2 engine: computes h2(n-1) at iter n =================
        // K = [h1(64) | h2(64)]: chunk kc -> 16 rows from W2 (kc<4) or U2 (kc>=4)
        __half2 ww[4][8];
        const float* WU = (kc < 4) ? W2 : U2;
        const int r0 = (kc & 3) * 16;
        #pragma unroll
        for (int g = 0; g < 4; ++g) {
            const int col = g * HH + u;
            #pragma unroll
            for (int j = 0; j < 8; ++j)
                ww[g][j] = __floats2half2_rn(WU[(r0 + 2*j) * GG + col],
                                             WU[(r0 + 2*j + 1) * GG + col]);
        }
        const float bz  = b2[sg * HH + u];
        const float wdu = Wd[u];
        float c2 = 0.f;

        for (int n = 0; n < TT + 2; ++n) {
            const int p = n & 1;
            if (n >= 1 && n <= TT) {
                const __half* hsrc = (kc < 4) ? h1b[p] : h2b[p];
                float4 hv0 = ((const float4*)hsrc)[(kc & 3) * 2];
                float4 hv1 = ((const float4*)hsrc)[(kc & 3) * 2 + 1];
                __half2 hh[8] = { f_as_h2(hv0.x), f_as_h2(hv0.y), f_as_h2(hv0.z), f_as_h2(hv0.w),
                                  f_as_h2(hv1.x), f_as_h2(hv1.y), f_as_h2(hv1.z), f_as_h2(hv1.w) };
                float ag[4];
                #pragma unroll
                for (int g = 0; g < 4; ++g) {
                    __half2 sa = __float2half2_rn(0.f), sb = sa;
                    #pragma unroll
                    for (int j = 0; j < 4; ++j) sa = __hfma2(ww[g][j], hh[j], sa);
                    #pragma unroll
                    for (int j = 4; j < 8; ++j) sb = __hfma2(ww[g][j], hh[j], sb);
                    __half2 s = __hadd2(sa, sb);
                    ag[g] = __low2float(s) + __high2float(s);
                }
                float s0 = (kc & 1) ? ag[0] : ag[2];
                float s1 = (kc & 1) ? ag[1] : ag[3];
                float t0 = __shfl_xor(s0, 8, 64);
                float t1 = __shfl_xor(s1, 8, 64);
                float ga = ((kc & 1) ? ag[2] : ag[0]) + t0;
                float gb = ((kc & 1) ? ag[3] : ag[1]) + t1;
                const bool hi2 = ((kc >> 1) & 1);
                float ms = hi2 ? ga : gb;
                float mk = hi2 ? gb : ga;
                float zp = mk + __shfl_xor(ms, 16, 64);
                float z  = zp + __shfl_xor(zp, 32, 64) + bz;

                float a = act(z, istanh);
                float x8  = __shfl_xor(a, 8, 64);
                float x16 = __shfl_xor(a, 16, 64);
                float x24 = __shfl_xor(x8, 16, 64);
                float gi = (sg==0) ? a   : (sg==1) ? x16 : (sg==2) ? x8  : x24;
                float gf = (sg==0) ? x16 : (sg==1) ? a   : (sg==2) ? x24 : x8;
                float gc = (sg==0) ? x8  : (sg==1) ? x24 : (sg==2) ? a   : x16;
                float go = (sg==0) ? x24 : (sg==1) ? x8  : (sg==2) ? x16 : a;
                c2 = gf * c2 + gi * gc;
                float h = go * tanhf_(c2);
                if (kc == 0) h2b[p ^ 1][u] = __float2half(h);

                // projection partial over this wave's 8 units (kc0 lanes 0..7)
                float v = (kc == 0) ? h * wdu : 0.f;
                v += __shfl_xor(v, 1, 64);
                v += __shfl_xor(v, 2, 64);
                v += __shfl_xor(v, 4, 64);
                if (l == 0) pbuf[p ^ 1][wid - 8] = v;
            }
            __syncthreads();
        }
    }
}

extern "C" void kernel_launch(void* const* d_in, const int* in_sizes, int n_in,
                              void* d_out, int out_size, void* d_ws, size_t ws_size,
                              hipStream_t stream) {
    const float* x  = (const float*)d_in[0];
    const float* W1 = (const float*)d_in[1];
    const float* U1 = (const float*)d_in[2];
    const float* b1 = (const float*)d_in[3];
    const float* W2 = (const float*)d_in[4];
    const float* U2 = (const float*)d_in[5];
    const float* b2 = (const float*)d_in[6];
    const float* Wd = (const float*)d_in[7];
    const float* bd = (const float*)d_in[8];
    float* out = (float*)d_out;

    dlstm_kernel<<<dim3(BB), dim3(1024), 0, stream>>>(
        x, W1, U1, b1, W2, U2, b2, Wd, bd, out);
}